// Round 15
// baseline (1176.537 us; speedup 1.0000x reference)
//
#include <hip/hip_runtime.h>

typedef unsigned short u16;
typedef __attribute__((ext_vector_type(4))) unsigned short u16x4;
typedef __attribute__((ext_vector_type(8))) unsigned short u16x8;
typedef __attribute__((ext_vector_type(4))) short s16x4;
typedef __attribute__((ext_vector_type(8))) short s16x8;
typedef __attribute__((ext_vector_type(16))) float f32x16;

constexpr int NU_ = 200000, NI_ = 100000;
constexpr int E_UB = 1000000, E_IU = 1000000, E_II = 500000;
constexpr int SAP = 132;  // final_upd weight stride

__device__ inline float bf2f(u16 v) { return __uint_as_float(((unsigned)v) << 16); }
__device__ inline u16 f2bf(float f) {
    unsigned u = __float_as_uint(f);
    return (u16)((u + 0x7FFFu + ((u >> 16) & 1u)) >> 16);  // RNE
}

// ================= merged CSR build =================
__global__ void deg_all(const int* __restrict__ d0, int E0, int* __restrict__ g0,
                        const int* __restrict__ d1, int E1, int* __restrict__ g1,
                        const int* __restrict__ d2, int E2, int* __restrict__ g2) {
    int i = blockIdx.x * 256 + threadIdx.x;
    if (i < E0) { atomicAdd(&g0[d0[i]], 1); return; }
    i -= E0;
    if (i < E1) { atomicAdd(&g1[d1[i]], 1); return; }
    i -= E1;
    if (i < E2) atomicAdd(&g2[d2[i]], 1);
}

__global__ void scanA_all(const int* __restrict__ g0, int N0, const int* __restrict__ g1, int N1,
                          const int* __restrict__ g2, int N2, int* __restrict__ bsum3) {
    __shared__ int s[256];
    const int* deg = blockIdx.y == 0 ? g0 : (blockIdx.y == 1 ? g1 : g2);
    int N = blockIdx.y == 0 ? N0 : (blockIdx.y == 1 ? N1 : N2);
    int* bsum = bsum3 + blockIdx.y * 256;
    int b = blockIdx.x, t = threadIdx.x;
    int base = b * 1024 + t * 4;
    int v = 0;
#pragma unroll
    for (int j = 0; j < 4; ++j) { int i = base + j; if (i < N) v += deg[i]; }
    s[t] = v; __syncthreads();
    for (int off = 1; off < 256; off <<= 1) {
        int x = (t >= off) ? s[t - off] : 0;
        __syncthreads();
        s[t] += x;
        __syncthreads();
    }
    if (t == 255) bsum[b] = s[255];
}

__global__ void scanB_all(int* __restrict__ bsum3, int nb) {
    __shared__ int s[256];
    int* bsum = bsum3 + blockIdx.x * 256;
    int t = threadIdx.x;
    int v = (t < nb) ? bsum[t] : 0;
    s[t] = v; __syncthreads();
    for (int off = 1; off < 256; off <<= 1) {
        int x = (t >= off) ? s[t - off] : 0;
        __syncthreads();
        s[t] += x;
        __syncthreads();
    }
    if (t < nb) bsum[t] = s[t] - v;  // exclusive
}

__global__ void scanC_all(const int* __restrict__ g0, int N0, int* __restrict__ rp0, int E0,
                          const int* __restrict__ g1, int N1, int* __restrict__ rp1, int E1,
                          const int* __restrict__ g2, int N2, int* __restrict__ rp2, int E2,
                          const int* __restrict__ bsum3) {
    __shared__ int s[256];
    const int* deg = blockIdx.y == 0 ? g0 : (blockIdx.y == 1 ? g1 : g2);
    int N = blockIdx.y == 0 ? N0 : (blockIdx.y == 1 ? N1 : N2);
    int* rp = blockIdx.y == 0 ? rp0 : (blockIdx.y == 1 ? rp1 : rp2);
    int E = blockIdx.y == 0 ? E0 : (blockIdx.y == 1 ? E1 : E2);
    const int* boff = bsum3 + blockIdx.y * 256;
    int b = blockIdx.x, t = threadIdx.x;
    int base = b * 1024 + t * 4;
    int d[4]; int v = 0;
#pragma unroll
    for (int j = 0; j < 4; ++j) { int i = base + j; d[j] = (i < N) ? deg[i] : 0; v += d[j]; }
    s[t] = v; __syncthreads();
    for (int off = 1; off < 256; off <<= 1) {
        int x = (t >= off) ? s[t - off] : 0;
        __syncthreads();
        s[t] += x;
        __syncthreads();
    }
    int ex = boff[b] + s[t] - v;
#pragma unroll
    for (int j = 0; j < 4; ++j) { int i = base + j; if (i < N) rp[i] = ex; ex += d[j]; }
    if (b == 0 && t == 0) rp[N] = E;
}

__global__ void inv_all(const int* __restrict__ deg, float* __restrict__ inv, int N) {
    int i = blockIdx.x * 256 + threadIdx.x;
    if (i < N) inv[i] = 1.0f / fmaxf((float)deg[i], 1.0f);
}

__global__ void fill_all(const int* __restrict__ s0, const int* __restrict__ d0, int E0,
                         const int* __restrict__ rp0, int* __restrict__ c0, int* __restrict__ o0,
                         const int* __restrict__ s1, const int* __restrict__ d1, int E1,
                         const int* __restrict__ rp1, int* __restrict__ c1, int* __restrict__ o1,
                         const int* __restrict__ s2, const int* __restrict__ d2, int E2,
                         const int* __restrict__ rp2, int* __restrict__ c2, int* __restrict__ o2) {
    int i = blockIdx.x * 256 + threadIdx.x;
    if (i < E0) { int d = d0[i]; int p = atomicAdd(&c0[d], 1); o0[rp0[d] + p] = s0[i]; return; }
    i -= E0;
    if (i < E1) { int d = d1[i]; int p = atomicAdd(&c1[d], 1); o1[rp1[d] + p] = s1[i]; return; }
    i -= E1;
    if (i < E2) { int d = d2[i]; int p = atomicAdd(&c2[d], 1); o2[rp2[d] + p] = s2[i]; }
}

// ================= conversions =================
__global__ void cvt_kernel(const float* __restrict__ in, u16* __restrict__ out, int n4) {
    int i = blockIdx.x * 256 + threadIdx.x;
    if (i < n4) {
        float4 v = reinterpret_cast<const float4*>(in)[i];
        u16x4 o = { f2bf(v.x), f2bf(v.y), f2bf(v.z), f2bf(v.w) };
        reinterpret_cast<u16x4*>(out)[i] = o;
    }
}

struct WtJob { const float* a; const float* b; u16* d; int K; int N; };
struct WtJobs { WtJob j[21]; };

// src [K][N] f32 (+optional second src summed) -> dst [N][K] bf16
__global__ void wt_all(WtJobs jobs) {
    WtJob w = jobs.j[blockIdx.y];
    int i = blockIdx.x * 256 + threadIdx.x;
    if (i < w.K * w.N) {
        int k = i / w.N, n = i - k * w.N;
        float v = w.a[i];
        if (w.b) v += w.b[i];
        w.d[(size_t)n * w.K + k] = f2bf(v);
    }
}

// ================= standalone gather: 16B loads per lane (rounds 12-14, verified) =================
template<int K, bool F32SRC>
__global__ __launch_bounds__(256, 8) void gather_kernel(
    const void* __restrict__ xsrc, const int* __restrict__ rp, const int* __restrict__ col,
    const float* __restrict__ inv, u16* __restrict__ agg, int N) {
    constexpr int LPR = F32SRC ? (K / 4) : (K / 8);
    long long gt = (long long)blockIdx.x * 256 + threadIdx.x;
    int node = (int)(gt / LPR);
    int lane = (int)(gt % LPR);
    if (node >= N) return;
    int s = rp[node], e = rp[node + 1];
    float sc = inv[node];
    if constexpr (F32SRC) {
        float a0 = 0.f, a1 = 0.f, a2 = 0.f, a3 = 0.f;
        for (; s + 4 <= e; s += 4) {
            int c0 = col[s], c1 = col[s + 1], c2 = col[s + 2], c3 = col[s + 3];
            float4 v0 = reinterpret_cast<const float4*>(xsrc)[(size_t)c0 * LPR + lane];
            float4 v1 = reinterpret_cast<const float4*>(xsrc)[(size_t)c1 * LPR + lane];
            float4 v2 = reinterpret_cast<const float4*>(xsrc)[(size_t)c2 * LPR + lane];
            float4 v3 = reinterpret_cast<const float4*>(xsrc)[(size_t)c3 * LPR + lane];
            a0 += (v0.x + v1.x) + (v2.x + v3.x);
            a1 += (v0.y + v1.y) + (v2.y + v3.y);
            a2 += (v0.z + v1.z) + (v2.z + v3.z);
            a3 += (v0.w + v1.w) + (v2.w + v3.w);
        }
        for (; s < e; ++s) {
            int c = col[s];
            float4 v = reinterpret_cast<const float4*>(xsrc)[(size_t)c * LPR + lane];
            a0 += v.x; a1 += v.y; a2 += v.z; a3 += v.w;
        }
        u16x4 o = { f2bf(a0 * sc), f2bf(a1 * sc), f2bf(a2 * sc), f2bf(a3 * sc) };
        reinterpret_cast<u16x4*>(agg)[(size_t)node * LPR + lane] = o;
    } else {
        float a[8];
#pragma unroll
        for (int j = 0; j < 8; ++j) a[j] = 0.f;
        for (; s + 4 <= e; s += 4) {
            int c0 = col[s], c1 = col[s + 1], c2 = col[s + 2], c3 = col[s + 3];
            u16x8 v0 = reinterpret_cast<const u16x8*>(xsrc)[(size_t)c0 * LPR + lane];
            u16x8 v1 = reinterpret_cast<const u16x8*>(xsrc)[(size_t)c1 * LPR + lane];
            u16x8 v2 = reinterpret_cast<const u16x8*>(xsrc)[(size_t)c2 * LPR + lane];
            u16x8 v3 = reinterpret_cast<const u16x8*>(xsrc)[(size_t)c3 * LPR + lane];
#pragma unroll
            for (int j = 0; j < 8; ++j)
                a[j] += (bf2f(v0[j]) + bf2f(v1[j])) + (bf2f(v2[j]) + bf2f(v3[j]));
        }
        for (; s < e; ++s) {
            int c = col[s];
            u16x8 v = reinterpret_cast<const u16x8*>(xsrc)[(size_t)c * LPR + lane];
#pragma unroll
            for (int j = 0; j < 8; ++j) a[j] += bf2f(v[j]);
        }
        u16x8 o;
#pragma unroll
        for (int j = 0; j < 8; ++j) o[j] = f2bf(a[j] * sc);
        reinterpret_cast<u16x8*>(agg)[(size_t)node * LPR + lane] = o;
    }
}

// ================= column-split merged MFMA update =================
// Block = 512 thr (8 waves), 128 rows x 64 cols (blockIdx.y in {0,1} picks col half).
// Only the needed weight HALVES in LDS (16 KB each) -> 4 blocks/CU = 32 waves/CU.
// All updates out-of-place (ping-pong regions) so col-split has no cross-block race.
// mfma_f32_32x32x16_bf16; C/D: col=lane&31, row=(r&3)+8*(r>>2)+4*(lane>>5).

__device__ inline s16x8 afrag_bf(const u16* __restrict__ A, int stride, int row, int e) {
    const u16* pa = A + (size_t)row * stride + e;
    s16x4 q0 = *reinterpret_cast<const s16x4*>(pa);
    s16x4 q1 = *reinterpret_cast<const s16x4*>(pa + 8);
    return s16x8{ q0.x, q0.y, q0.z, q0.w, q1.x, q1.y, q1.z, q1.w };
}

__device__ inline s16x8 afrag_f32(const float* __restrict__ A, int stride, int row, int e) {
    const float* pa = A + (size_t)row * stride + e;
    float4 f0 = *reinterpret_cast<const float4*>(pa);
    float4 f1 = *reinterpret_cast<const float4*>(pa + 8);
    return s16x8{ (short)f2bf(f0.x), (short)f2bf(f0.y), (short)f2bf(f0.z), (short)f2bf(f0.w),
                  (short)f2bf(f1.x), (short)f2bf(f1.y), (short)f2bf(f1.z), (short)f2bf(f1.w) };
}

// stage weight half [nBase..nBase+64) x K -> sW [64][K u16], 8B-granule XOR swizzle
template<int K, int SWZ>
__device__ inline void stage_w64(const u16* __restrict__ Wt, int nBase, u16* sW) {
    constexpr int CH = K / 4;
    constexpr int TOT = 64 * CH;
#pragma unroll
    for (int i = threadIdx.x; i < TOT; i += 512) {
        int n = i / CH, g = i - n * CH;
        int gs = g ^ (n & SWZ);
        *reinterpret_cast<u16x4*>(sW + n * K + gs * 4) =
            *reinterpret_cast<const u16x4*>(Wt + (size_t)(nBase + n) * K + g * 4);
    }
}

template<int K, int SWZ>
__device__ inline s16x8 bfrag64(const u16* sW, int nl, int e) {
    const u16* row = sW + nl * K;
    int m = nl & SWZ;
    int g0 = ((e >> 2) ^ m) << 2;
    int g1 = (((e >> 2) + 2) ^ m) << 2;
    s16x4 r0 = *reinterpret_cast<const s16x4*>(row + g0);
    s16x4 r1 = *reinterpret_cast<const s16x4*>(row + g1);
    return s16x8{ r0.x, r0.y, r0.z, r0.w, r1.x, r1.y, r1.z, r1.w };
}

// user: out = relu(agg@Wl + self@Wr + b); out DISJOINT from all inputs
template<int KS, bool SELF_F32>
__global__ __launch_bounds__(512, 8) void user_cs(
    const u16* __restrict__ agg, const u16* __restrict__ WlT, const float* __restrict__ bias,
    const u16* __restrict__ WrT, const void* __restrict__ xself,
    u16* __restrict__ out, int N) {
    __shared__ u16 sW0[64 * 128];
    __shared__ u16 sW1[64 * KS];
    constexpr int SWS = (KS == 128) ? 31 : 15;
    f32x16 acc;
    const int lane = threadIdx.x & 63, wid = threadIdx.x >> 6;
    const int lm = lane & 31, hi = lane >> 5;
    const int rb = wid >> 1, cbi = wid & 1;
    const int colBase = blockIdx.y * 64;
    const int rowBase = blockIdx.x * 128;
    const int arow = min(rowBase + rb * 32 + lm, N - 1);
    const int nl = cbi * 32 + lm;
    const int colv = colBase + nl;
    {
        float bv = bias[colv];
#pragma unroll
        for (int i = 0; i < 16; ++i) acc[i] = bv;
    }
    stage_w64<128, 31>(WlT, colBase, sW0);
    stage_w64<KS, SWS>(WrT, colBase, sW1);
    __syncthreads();
#pragma unroll
    for (int kc = 0; kc < 128; kc += 16) {
        const int e = kc + 4 * hi;
        s16x8 aA = afrag_bf(agg, 128, arow, e);
        s16x8 aS;
        if (kc < KS) {
            if constexpr (SELF_F32) aS = afrag_f32((const float*)xself, KS, arow, e);
            else aS = afrag_bf((const u16*)xself, KS, arow, e);
        }
        acc = __builtin_amdgcn_mfma_f32_32x32x16_bf16(aA, bfrag64<128, 31>(sW0, nl, e), acc, 0, 0, 0);
        if (kc < KS)
            acc = __builtin_amdgcn_mfma_f32_32x32x16_bf16(aS, bfrag64<KS, SWS>(sW1, nl, e), acc, 0, 0, 0);
    }
#pragma unroll
    for (int r = 0; r < 16; ++r) {
        int row = rowBase + rb * 32 + (r & 3) + 8 * (r >> 2) + 4 * hi;
        if (row < N) out[(size_t)row * 128 + colv] = f2bf(fmaxf(acc[r], 0.f));
    }
}

// item: out = relu(0.5*(aggA@WlA + aggB@WlB + self@Wsum + bA + bB)); out != inputs
template<int KA>
__global__ __launch_bounds__(512, 8) void item_cs(
    const u16* __restrict__ aggA, const u16* __restrict__ WlAT, const float* __restrict__ bA,
    const u16* __restrict__ aggB, const u16* __restrict__ WlBT, const float* __restrict__ bB,
    const u16* __restrict__ WsumT, const u16* __restrict__ xself,
    u16* __restrict__ out, int N) {
    __shared__ u16 sW0[64 * KA];
    __shared__ u16 sW1[64 * 128];
    constexpr int SWA = (KA == 128) ? 31 : 15;
    f32x16 acc;
    const int lane = threadIdx.x & 63, wid = threadIdx.x >> 6;
    const int lm = lane & 31, hi = lane >> 5;
    const int rb = wid >> 1, cbi = wid & 1;
    const int colBase = blockIdx.y * 64;
    const int rowBase = blockIdx.x * 128;
    const int arow = min(rowBase + rb * 32 + lm, N - 1);
    const int nl = cbi * 32 + lm;
    const int colv = colBase + nl;
    {
        float bv = bA[colv] + bB[colv];
#pragma unroll
        for (int i = 0; i < 16; ++i) acc[i] = bv;
    }
    stage_w64<KA, SWA>(WlAT, colBase, sW0);
    stage_w64<128, 31>(WlBT, colBase, sW1);
    __syncthreads();
#pragma unroll
    for (int kc = 0; kc < 128; kc += 16) {
        const int e = kc + 4 * hi;
        s16x8 aB = afrag_bf(aggB, 128, arow, e);
        s16x8 aA;
        if (kc < KA) aA = afrag_bf(aggA, KA, arow, e);
        acc = __builtin_amdgcn_mfma_f32_32x32x16_bf16(aB, bfrag64<128, 31>(sW1, nl, e), acc, 0, 0, 0);
        if (kc < KA)
            acc = __builtin_amdgcn_mfma_f32_32x32x16_bf16(aA, bfrag64<KA, SWA>(sW0, nl, e), acc, 0, 0, 0);
    }
    __syncthreads();  // done reading sW1
    stage_w64<128, 31>(WsumT, colBase, sW1);
    __syncthreads();
#pragma unroll
    for (int kc = 0; kc < 128; kc += 16) {
        const int e = kc + 4 * hi;
        s16x8 aS = afrag_bf(xself, 128, arow, e);
        acc = __builtin_amdgcn_mfma_f32_32x32x16_bf16(aS, bfrag64<128, 31>(sW1, nl, e), acc, 0, 0, 0);
    }
#pragma unroll
    for (int r = 0; r < 16; ++r) {
        int row = rowBase + rb * 32 + (r & 3) + 8 * (r >> 2) + 4 * hi;
        if (row < N) out[(size_t)row * 128 + colv] = f2bf(fmaxf(0.5f * acc[r], 0.f));
    }
}

// ================= final 128->64 linear, f32 out (rounds 11-14, verified) =================
template<int K, int NCOL>
__device__ inline void stage_w_sap(const u16* __restrict__ Wt, u16* sW) {
    constexpr int CH = K / 4;
    constexpr int TOT = NCOL * CH;
#pragma unroll
    for (int i = threadIdx.x; i < TOT; i += 256) {
        int n = i / CH, c = i - n * CH;
        *reinterpret_cast<u16x4*>(sW + n * SAP + c * 4) =
            *reinterpret_cast<const u16x4*>(Wt + (size_t)n * K + c * 4);
    }
}

__global__ __launch_bounds__(256, 4) void final_upd(
    const u16* __restrict__ x, const u16* __restrict__ WfT, const float* __restrict__ bias,
    float* __restrict__ out, int N) {
    __shared__ u16 sW[64 * SAP];
    f32x16 acc;
    const int lane = threadIdx.x & 63, wid = threadIdx.x >> 6;
    const int lm = lane & 31, hi = lane >> 5;
    const int rb = wid / 2;
    const int rowBase = blockIdx.x * 64;
    const int arow = min(rowBase + rb * 32 + lm, N - 1);
    {
        float bv = bias[(wid % 2) * 32 + lm];
#pragma unroll
        for (int i = 0; i < 16; ++i) acc[i] = bv;
    }
    stage_w_sap<128, 64>(WfT, sW);
    __syncthreads();
    const int cb = wid % 2;
#pragma unroll
    for (int kc = 0; kc < 128; kc += 16) {
        const int e = kc + 4 * hi;
        s16x8 a = afrag_bf(x, 128, arow, e);
        const u16* pb = sW + (cb * 32 + lm) * SAP + e;
        s16x4 r0 = *reinterpret_cast<const s16x4*>(pb);
        s16x4 r1 = *reinterpret_cast<const s16x4*>(pb + 8);
        s16x8 b = { r0.x, r0.y, r0.z, r0.w, r1.x, r1.y, r1.z, r1.w };
        acc = __builtin_amdgcn_mfma_f32_32x32x16_bf16(a, b, acc, 0, 0, 0);
    }
    {
        int colv = cb * 32 + lm;
#pragma unroll
        for (int r = 0; r < 16; ++r) {
            int row = rowBase + rb * 32 + (r & 3) + 8 * (r >> 2) + 4 * hi;
            if (row < N) out[(size_t)row * 64 + colv] = acc[r];
        }
    }
}

// ================= host =================
extern "C" void kernel_launch(void* const* d_in, const int* in_sizes, int n_in,
                              void* d_out, int out_size, void* d_ws, size_t ws_size,
                              hipStream_t stream) {
    const float* x_user = (const float*)d_in[0];
    const float* x_item = (const float*)d_in[1];
    const int* ub_src = (const int*)d_in[2];
    const int* ub_dst = (const int*)d_in[3];
    const int* iu_src = (const int*)d_in[4];
    const int* iu_dst = (const int*)d_in[5];
    const int* ii_src = (const int*)d_in[6];
    const int* ii_dst = (const int*)d_in[7];
    const float* W1l_ub = (const float*)d_in[8];
    const float* W1r_ub = (const float*)d_in[9];
    const float* b1_ub = (const float*)d_in[10];
    const float* W1l_iu = (const float*)d_in[11];
    const float* W1r_iu = (const float*)d_in[12];
    const float* b1_iu = (const float*)d_in[13];
    const float* W1l_ii = (const float*)d_in[14];
    const float* W1r_ii = (const float*)d_in[15];
    const float* b1_ii = (const float*)d_in[16];
    const float* W23l = (const float*)d_in[17];
    const float* W23r = (const float*)d_in[18];
    const float* b23 = (const float*)d_in[19];
    const float* Wf_user = (const float*)d_in[20];
    const float* bf_user = (const float*)d_in[21];
    const float* Wf_item = (const float*)d_in[22];
    const float* bf_item = (const float*)d_in[23];

    // ---- workspace layout (~168 MB + optional 25.6) ----
    char* p = (char*)d_ws;
    u16* U0  = (u16*)p;     p += (size_t)NU_ * 128 * 2;  // 51.2 MB (xu / agg ping-pong A)
    u16* xiA = (u16*)p;     p += (size_t)NI_ * 128 * 2;  // 25.6
    u16* xi0 = (u16*)p;     p += (size_t)NI_ * 128 * 2;  // 25.6 (x_item bf16)
    u16* U1  = (u16*)p;     p += (size_t)NU_ * 128 * 2;  // 51.2 (agg / xu ping-pong B; deg3 alias)
    u16* wt  = (u16*)p;     p += (size_t)344064 * 2;     // 0.69
    float* inv3 = (float*)p; p += (size_t)(NU_ + 2 * NI_) * 4;  // inv_iu|inv_ub|inv_ii
    int* rp_iu = (int*)p;  p += (size_t)(NU_ + 4) * 4;
    int* rp_ub = (int*)p;  p += (size_t)(NI_ + 4) * 4;
    int* rp_ii = (int*)p;  p += (size_t)(NI_ + 4) * 4;
    int* col_iu = (int*)p; p += (size_t)E_IU * 4;
    int* col_ub = (int*)p; p += (size_t)E_UB * 4;
    int* col_ii = (int*)p; p += (size_t)E_II * 4;
    int* bsum3 = (int*)p;  p += 3 * 256 * 4;
    u16* xu0b = nullptr;  // optional bf16 x_user
    {
        size_t used = (size_t)(p - (char*)d_ws);
        if (used + (size_t)NU_ * 64 * 2 <= ws_size) xu0b = (u16*)p;
    }
    float* inv_iu = inv3;
    float* inv_ub = inv3 + NU_;
    float* inv_ii = inv3 + NU_ + NI_;
    // deg3 aliases U1 head (CSR completes before gathers write aggs)
    int* deg3 = (int*)U1;
    int* deg_iu = deg3, *deg_ub = deg3 + NU_, *deg_ii = deg3 + NU_ + NI_;
    // d_out: agg_iu [NU][128] bf16 + xiB [NI][128] bf16; dead before finals write
    u16* agg_iu = (u16*)d_out;
    u16* xiB = (u16*)((char*)d_out + (size_t)NU_ * 128 * 2);
    // region halves for item aggs
    u16* U0a = U0, *U0b = U0 + (size_t)NI_ * 128;
    u16* U1a = U1, *U1b = U1 + (size_t)NI_ * 128;

    // weight slots (bf16, transposed [N][K])
    u16* wt_W1l_ub = wt + 0;
    u16* wt_W1l_iu = wt + 24576;
    u16* wt_W1r_iu = wt + 40960;
    u16* wt_W1l_ii = wt + 49152;
    u16* wt_W23l   = wt + 81920;    // 6 x 16384
    u16* wt_W23r   = wt + 180224;   // 6 x 16384
    u16* wt_Wf_u   = wt + 278528;
    u16* wt_Wf_i   = wt + 286720;
    u16* wt_Wsum   = wt + 294912;   // 3 x 16384

    // ---- CSR build (merged) ----
    hipMemsetAsync(deg3, 0, (size_t)(NU_ + 2 * NI_) * 4, stream);
    const int Etot = E_IU + E_UB + E_II;
    deg_all<<<(Etot + 255) / 256, 256, 0, stream>>>(iu_dst, E_IU, deg_iu, ub_dst, E_UB, deg_ub,
                                                    ii_dst, E_II, deg_ii);
    const int NB = 196;  // max nb over relations (NU/1024)
    scanA_all<<<dim3(NB, 3), 256, 0, stream>>>(deg_iu, NU_, deg_ub, NI_, deg_ii, NI_, bsum3);
    scanB_all<<<3, 256, 0, stream>>>(bsum3, NB);
    scanC_all<<<dim3(NB, 3), 256, 0, stream>>>(deg_iu, NU_, rp_iu, E_IU,
                                               deg_ub, NI_, rp_ub, E_UB,
                                               deg_ii, NI_, rp_ii, E_II, bsum3);
    inv_all<<<(NU_ + 2 * NI_ + 255) / 256, 256, 0, stream>>>(deg3, inv3, NU_ + 2 * NI_);
    hipMemsetAsync(deg3, 0, (size_t)(NU_ + 2 * NI_) * 4, stream);  // cursors
    fill_all<<<(Etot + 255) / 256, 256, 0, stream>>>(
        iu_src, iu_dst, E_IU, rp_iu, deg_iu, col_iu,
        ub_src, ub_dst, E_UB, rp_ub, deg_ub, col_ub,
        ii_src, ii_dst, E_II, rp_ii, deg_ii, col_ii);

    // ---- conversions (merged weight prep) ----
    cvt_kernel<<<(NI_ * 32 + 255) / 256, 256, 0, stream>>>(x_item, xi0, NI_ * 32);
    if (xu0b) cvt_kernel<<<(NU_ * 16 + 255) / 256, 256, 0, stream>>>(x_user, xu0b, NU_ * 16);
    {
        WtJobs J;
        int idx = 0;
        J.j[idx++] = { W1l_ub, nullptr, wt_W1l_ub, 64, 128 };
        J.j[idx++] = { W1l_iu, nullptr, wt_W1l_iu, 128, 128 };
        J.j[idx++] = { W1r_iu, nullptr, wt_W1r_iu, 64, 128 };
        J.j[idx++] = { W1l_ii, nullptr, wt_W1l_ii, 128, 128 };
        for (int m = 0; m < 6; ++m) J.j[idx++] = { W23l + (size_t)m * 16384, nullptr, wt_W23l + (size_t)m * 16384, 128, 128 };
        for (int m = 0; m < 6; ++m) J.j[idx++] = { W23r + (size_t)m * 16384, nullptr, wt_W23r + (size_t)m * 16384, 128, 128 };
        J.j[idx++] = { Wf_user, nullptr, wt_Wf_u, 128, 64 };
        J.j[idx++] = { Wf_item, nullptr, wt_Wf_i, 128, 64 };
        J.j[idx++] = { W1r_ub, W1r_ii, wt_Wsum + 0, 128, 128 };
        J.j[idx++] = { W23r + 0 * 16384, W23r + 2 * 16384, wt_Wsum + 16384, 128, 128 };
        J.j[idx++] = { W23r + 3 * 16384, W23r + 5 * 16384, wt_Wsum + 32768, 128, 128 };
        wt_all<<<dim3(64, 21), 256, 0, stream>>>(J);
    }

    const dim3 gU(( NU_ + 127) / 128, 2);   // 1563 x 2
    const dim3 gI((NI_ + 127) / 128, 2);    // 782 x 2
    const int gUf = (NU_ + 63) / 64, gIf = (NI_ + 63) / 64;
    const int ggI_b128 = (NI_ * 16 + 255) / 256;
    const int ggU_b128 = (NU_ * 16 + 255) / 256;
    const int ggI_b64  = (NI_ * 8 + 255) / 256;
    const int ggI_f64  = (NI_ * 16 + 255) / 256;

    // ---- layer 1: aggs -> U1, xu1 -> U0, xi1 -> xiA ----
    if (xu0b)
        gather_kernel<64, false><<<ggI_b64, 256, 0, stream>>>(xu0b, rp_ub, col_ub, inv_ub, U1a, NI_);
    else
        gather_kernel<64, true><<<ggI_f64, 256, 0, stream>>>(x_user, rp_ub, col_ub, inv_ub, U1a, NI_);
    gather_kernel<128, false><<<ggI_b128, 256, 0, stream>>>(xi0, rp_ii, col_ii, inv_ii, U1b, NI_);
    gather_kernel<128, false><<<ggU_b128, 256, 0, stream>>>(xi0, rp_iu, col_iu, inv_iu, agg_iu, NU_);
    item_cs<64><<<gI, 512, 0, stream>>>(
        U1a, wt_W1l_ub, b1_ub, U1b, wt_W1l_ii, b1_ii, wt_Wsum + 0, xi0, xiA, NI_);
    if (xu0b)
        user_cs<64, false><<<gU, 512, 0, stream>>>(agg_iu, wt_W1l_iu, b1_iu, wt_W1r_iu, xu0b, U0, NU_);
    else
        user_cs<64, true><<<gU, 512, 0, stream>>>(agg_iu, wt_W1l_iu, b1_iu, wt_W1r_iu, x_user, U0, NU_);

    // ---- layers 2-3 (xu ping-pong U0 -> U1 -> U0; aggs use the dead region) ----
    for (int l = 0; l < 2; ++l) {
        const u16* xu_in = (l == 0) ? U0 : U1;
        u16* agg_a = (l == 0) ? U1a : U0a;   // agg_ub slot (dead xu side)
        u16* agg_b = (l == 0) ? U1b : U0b;   // agg_ii slot
        u16* xu_out = (l == 0) ? U1 : U0;    // overwrites aggs after item consumed them
        const u16* xi_cur = (l == 0) ? xiA : xiB;
        u16* xi_nxt = (l == 0) ? xiB : xiA;
        const u16* wl_ub = wt_W23l + (size_t)(l * 3 + 0) * 16384;
        const u16* wl_iu = wt_W23l + (size_t)(l * 3 + 1) * 16384;
        const u16* wr_iu = wt_W23r + (size_t)(l * 3 + 1) * 16384;
        const u16* wl_ii = wt_W23l + (size_t)(l * 3 + 2) * 16384;
        const u16* wsum = wt_Wsum + (size_t)(l + 1) * 16384;
        const float* b_ub = b23 + (size_t)(l * 3 + 0) * 128;
        const float* b_iu = b23 + (size_t)(l * 3 + 1) * 128;
        const float* b_ii = b23 + (size_t)(l * 3 + 2) * 128;

        gather_kernel<128, false><<<ggI_b128, 256, 0, stream>>>(xu_in, rp_ub, col_ub, inv_ub, agg_a, NI_);
        gather_kernel<128, false><<<ggI_b128, 256, 0, stream>>>(xi_cur, rp_ii, col_ii, inv_ii, agg_b, NI_);
        gather_kernel<128, false><<<ggU_b128, 256, 0, stream>>>(xi_cur, rp_iu, col_iu, inv_iu, agg_iu, NU_);
        item_cs<128><<<gI, 512, 0, stream>>>(
            agg_a, wl_ub, b_ub, agg_b, wl_ii, b_ii, wsum, xi_cur, xi_nxt, NI_);
        user_cs<128, false><<<gU, 512, 0, stream>>>(
            agg_iu, wl_iu, b_iu, wr_iu, xu_in, xu_out, NU_);
    }

    // ---- finals: xu3 in U0, xi3 in xiA; overwrite agg_iu / xiB (dead) ----
    float* out = (float*)d_out;
    final_upd<<<gUf, 256, 0, stream>>>(U0, wt_Wf_u, bf_user, out, NU_);
    final_upd<<<gIf, 256, 0, stream>>>(xiA, wt_Wf_i, bf_item, out + (size_t)NU_ * 64, NI_);
}

// Round 16
// 994.235 us; speedup vs baseline: 1.1834x; 1.1834x over previous
//
#include <hip/hip_runtime.h>

typedef unsigned short u16;
typedef __attribute__((ext_vector_type(4))) unsigned short u16x4;
typedef __attribute__((ext_vector_type(8))) unsigned short u16x8;
typedef __attribute__((ext_vector_type(4))) short s16x4;
typedef __attribute__((ext_vector_type(8))) short s16x8;
typedef __attribute__((ext_vector_type(16))) float f32x16;

constexpr int NU_ = 200000, NI_ = 100000;
constexpr int E_UB = 1000000, E_IU = 1000000, E_II = 500000;
constexpr int SAP = 132;  // final_upd weight stride

__device__ inline float bf2f(u16 v) { return __uint_as_float(((unsigned)v) << 16); }
__device__ inline u16 f2bf(float f) {
    unsigned u = __float_as_uint(f);
    return (u16)((u + 0x7FFFu + ((u >> 16) & 1u)) >> 16);  // RNE
}

// ================= merged CSR build (round 15, verified) =================
__global__ void deg_all(const int* __restrict__ d0, int E0, int* __restrict__ g0,
                        const int* __restrict__ d1, int E1, int* __restrict__ g1,
                        const int* __restrict__ d2, int E2, int* __restrict__ g2) {
    int i = blockIdx.x * 256 + threadIdx.x;
    if (i < E0) { atomicAdd(&g0[d0[i]], 1); return; }
    i -= E0;
    if (i < E1) { atomicAdd(&g1[d1[i]], 1); return; }
    i -= E1;
    if (i < E2) atomicAdd(&g2[d2[i]], 1);
}

__global__ void scanA_all(const int* __restrict__ g0, int N0, const int* __restrict__ g1, int N1,
                          const int* __restrict__ g2, int N2, int* __restrict__ bsum3) {
    __shared__ int s[256];
    const int* deg = blockIdx.y == 0 ? g0 : (blockIdx.y == 1 ? g1 : g2);
    int N = blockIdx.y == 0 ? N0 : (blockIdx.y == 1 ? N1 : N2);
    int* bsum = bsum3 + blockIdx.y * 256;
    int b = blockIdx.x, t = threadIdx.x;
    int base = b * 1024 + t * 4;
    int v = 0;
#pragma unroll
    for (int j = 0; j < 4; ++j) { int i = base + j; if (i < N) v += deg[i]; }
    s[t] = v; __syncthreads();
    for (int off = 1; off < 256; off <<= 1) {
        int x = (t >= off) ? s[t - off] : 0;
        __syncthreads();
        s[t] += x;
        __syncthreads();
    }
    if (t == 255) bsum[b] = s[255];
}

__global__ void scanB_all(int* __restrict__ bsum3, int nb) {
    __shared__ int s[256];
    int* bsum = bsum3 + blockIdx.x * 256;
    int t = threadIdx.x;
    int v = (t < nb) ? bsum[t] : 0;
    s[t] = v; __syncthreads();
    for (int off = 1; off < 256; off <<= 1) {
        int x = (t >= off) ? s[t - off] : 0;
        __syncthreads();
        s[t] += x;
        __syncthreads();
    }
    if (t < nb) bsum[t] = s[t] - v;  // exclusive
}

__global__ void scanC_all(const int* __restrict__ g0, int N0, int* __restrict__ rp0, int E0,
                          const int* __restrict__ g1, int N1, int* __restrict__ rp1, int E1,
                          const int* __restrict__ g2, int N2, int* __restrict__ rp2, int E2,
                          const int* __restrict__ bsum3) {
    __shared__ int s[256];
    const int* deg = blockIdx.y == 0 ? g0 : (blockIdx.y == 1 ? g1 : g2);
    int N = blockIdx.y == 0 ? N0 : (blockIdx.y == 1 ? N1 : N2);
    int* rp = blockIdx.y == 0 ? rp0 : (blockIdx.y == 1 ? rp1 : rp2);
    int E = blockIdx.y == 0 ? E0 : (blockIdx.y == 1 ? E1 : E2);
    const int* boff = bsum3 + blockIdx.y * 256;
    int b = blockIdx.x, t = threadIdx.x;
    int base = b * 1024 + t * 4;
    int d[4]; int v = 0;
#pragma unroll
    for (int j = 0; j < 4; ++j) { int i = base + j; d[j] = (i < N) ? deg[i] : 0; v += d[j]; }
    s[t] = v; __syncthreads();
    for (int off = 1; off < 256; off <<= 1) {
        int x = (t >= off) ? s[t - off] : 0;
        __syncthreads();
        s[t] += x;
        __syncthreads();
    }
    int ex = boff[b] + s[t] - v;
#pragma unroll
    for (int j = 0; j < 4; ++j) { int i = base + j; if (i < N) rp[i] = ex; ex += d[j]; }
    if (b == 0 && t == 0) rp[N] = E;
}

__global__ void inv_all(const int* __restrict__ deg, float* __restrict__ inv, int N) {
    int i = blockIdx.x * 256 + threadIdx.x;
    if (i < N) inv[i] = 1.0f / fmaxf((float)deg[i], 1.0f);
}

__global__ void fill_all(const int* __restrict__ s0, const int* __restrict__ d0, int E0,
                         const int* __restrict__ rp0, int* __restrict__ c0, int* __restrict__ o0,
                         const int* __restrict__ s1, const int* __restrict__ d1, int E1,
                         const int* __restrict__ rp1, int* __restrict__ c1, int* __restrict__ o1,
                         const int* __restrict__ s2, const int* __restrict__ d2, int E2,
                         const int* __restrict__ rp2, int* __restrict__ c2, int* __restrict__ o2) {
    int i = blockIdx.x * 256 + threadIdx.x;
    if (i < E0) { int d = d0[i]; int p = atomicAdd(&c0[d], 1); o0[rp0[d] + p] = s0[i]; return; }
    i -= E0;
    if (i < E1) { int d = d1[i]; int p = atomicAdd(&c1[d], 1); o1[rp1[d] + p] = s1[i]; return; }
    i -= E1;
    if (i < E2) { int d = d2[i]; int p = atomicAdd(&c2[d], 1); o2[rp2[d] + p] = s2[i]; }
}

// ================= conversions =================
__global__ void cvt_kernel(const float* __restrict__ in, u16* __restrict__ out, int n4) {
    int i = blockIdx.x * 256 + threadIdx.x;
    if (i < n4) {
        float4 v = reinterpret_cast<const float4*>(in)[i];
        u16x4 o = { f2bf(v.x), f2bf(v.y), f2bf(v.z), f2bf(v.w) };
        reinterpret_cast<u16x4*>(out)[i] = o;
    }
}

struct WtJob { const float* a; const float* b; u16* d; int K; int N; };
struct WtJobs { WtJob j[21]; };

// src [K][N] f32 (+optional second src summed) -> dst [N][K] bf16
__global__ void wt_all(WtJobs jobs) {
    WtJob w = jobs.j[blockIdx.y];
    int i = blockIdx.x * 256 + threadIdx.x;
    if (i < w.K * w.N) {
        int k = i / w.N, n = i - k * w.N;
        float v = w.a[i];
        if (w.b) v += w.b[i];
        w.d[(size_t)n * w.K + k] = f2bf(v);
    }
}

// ================= standalone gather: 16B loads per lane (rounds 12-14, verified) =================
template<int K, bool F32SRC>
__global__ __launch_bounds__(256, 8) void gather_kernel(
    const void* __restrict__ xsrc, const int* __restrict__ rp, const int* __restrict__ col,
    const float* __restrict__ inv, u16* __restrict__ agg, int N) {
    constexpr int LPR = F32SRC ? (K / 4) : (K / 8);
    long long gt = (long long)blockIdx.x * 256 + threadIdx.x;
    int node = (int)(gt / LPR);
    int lane = (int)(gt % LPR);
    if (node >= N) return;
    int s = rp[node], e = rp[node + 1];
    float sc = inv[node];
    if constexpr (F32SRC) {
        float a0 = 0.f, a1 = 0.f, a2 = 0.f, a3 = 0.f;
        for (; s + 4 <= e; s += 4) {
            int c0 = col[s], c1 = col[s + 1], c2 = col[s + 2], c3 = col[s + 3];
            float4 v0 = reinterpret_cast<const float4*>(xsrc)[(size_t)c0 * LPR + lane];
            float4 v1 = reinterpret_cast<const float4*>(xsrc)[(size_t)c1 * LPR + lane];
            float4 v2 = reinterpret_cast<const float4*>(xsrc)[(size_t)c2 * LPR + lane];
            float4 v3 = reinterpret_cast<const float4*>(xsrc)[(size_t)c3 * LPR + lane];
            a0 += (v0.x + v1.x) + (v2.x + v3.x);
            a1 += (v0.y + v1.y) + (v2.y + v3.y);
            a2 += (v0.z + v1.z) + (v2.z + v3.z);
            a3 += (v0.w + v1.w) + (v2.w + v3.w);
        }
        for (; s < e; ++s) {
            int c = col[s];
            float4 v = reinterpret_cast<const float4*>(xsrc)[(size_t)c * LPR + lane];
            a0 += v.x; a1 += v.y; a2 += v.z; a3 += v.w;
        }
        u16x4 o = { f2bf(a0 * sc), f2bf(a1 * sc), f2bf(a2 * sc), f2bf(a3 * sc) };
        reinterpret_cast<u16x4*>(agg)[(size_t)node * LPR + lane] = o;
    } else {
        float a[8];
#pragma unroll
        for (int j = 0; j < 8; ++j) a[j] = 0.f;
        for (; s + 4 <= e; s += 4) {
            int c0 = col[s], c1 = col[s + 1], c2 = col[s + 2], c3 = col[s + 3];
            u16x8 v0 = reinterpret_cast<const u16x8*>(xsrc)[(size_t)c0 * LPR + lane];
            u16x8 v1 = reinterpret_cast<const u16x8*>(xsrc)[(size_t)c1 * LPR + lane];
            u16x8 v2 = reinterpret_cast<const u16x8*>(xsrc)[(size_t)c2 * LPR + lane];
            u16x8 v3 = reinterpret_cast<const u16x8*>(xsrc)[(size_t)c3 * LPR + lane];
#pragma unroll
            for (int j = 0; j < 8; ++j)
                a[j] += (bf2f(v0[j]) + bf2f(v1[j])) + (bf2f(v2[j]) + bf2f(v3[j]));
        }
        for (; s < e; ++s) {
            int c = col[s];
            u16x8 v = reinterpret_cast<const u16x8*>(xsrc)[(size_t)c * LPR + lane];
#pragma unroll
            for (int j = 0; j < 8; ++j) a[j] += bf2f(v[j]);
        }
        u16x8 o;
#pragma unroll
        for (int j = 0; j < 8; ++j) o[j] = f2bf(a[j] * sc);
        reinterpret_cast<u16x8*>(agg)[(size_t)node * LPR + lane] = o;
    }
}

// ================= 512-thread merged MFMA update (round 14, verified fastest) =================
// Block = 8 waves, 128 rows x 128 cols. Both weights in LDS (64 KB), 2 blocks/CU.
// mfma_f32_32x32x16_bf16; C/D: col=lane&31, row=(r&3)+8*(r>>2)+4*(lane>>5).

__device__ inline s16x8 afrag_bf(const u16* __restrict__ A, int stride, int row, int e) {
    const u16* pa = A + (size_t)row * stride + e;
    s16x4 q0 = *reinterpret_cast<const s16x4*>(pa);
    s16x4 q1 = *reinterpret_cast<const s16x4*>(pa + 8);
    return s16x8{ q0.x, q0.y, q0.z, q0.w, q1.x, q1.y, q1.z, q1.w };
}

__device__ inline s16x8 afrag_f32(const float* __restrict__ A, int stride, int row, int e) {
    const float* pa = A + (size_t)row * stride + e;
    float4 f0 = *reinterpret_cast<const float4*>(pa);
    float4 f1 = *reinterpret_cast<const float4*>(pa + 8);
    return s16x8{ (short)f2bf(f0.x), (short)f2bf(f0.y), (short)f2bf(f0.z), (short)f2bf(f0.w),
                  (short)f2bf(f1.x), (short)f2bf(f1.y), (short)f2bf(f1.z), (short)f2bf(f1.w) };
}

// stage transposed weight [128 n-rows][K] -> LDS slot [128][128 u16], granule-swizzled
template<int K, int SWZ>
__device__ inline void stage_w_swz(const u16* __restrict__ Wt, u16* sW) {
    constexpr int CH = K / 4;
    constexpr int TOT = 128 * CH;
#pragma unroll
    for (int i = threadIdx.x; i < TOT; i += 512) {
        int n = i / CH, g = i - n * CH;
        int gs = g ^ (n & SWZ);
        *reinterpret_cast<u16x4*>(sW + n * 128 + gs * 4) =
            *reinterpret_cast<const u16x4*>(Wt + (size_t)n * K + g * 4);
    }
}

template<int SWZ>
__device__ inline s16x8 bfrag(const u16* sW, int n, int e) {
    const u16* row = sW + n * 128;
    int m = n & SWZ;
    int g0 = ((e >> 2) ^ m) << 2;
    int g1 = (((e >> 2) + 2) ^ m) << 2;
    s16x4 r0 = *reinterpret_cast<const s16x4*>(row + g0);
    s16x4 r1 = *reinterpret_cast<const s16x4*>(row + g1);
    return s16x8{ r0.x, r0.y, r0.z, r0.w, r1.x, r1.y, r1.z, r1.w };
}

// user: out = relu(agg@Wl + self@Wr + b); out may alias xself (barrier before writes)
template<int KA, int KS, bool SELF_F32>
__global__ __launch_bounds__(512, 4) void user_upd512(
    const u16* __restrict__ agg, const u16* __restrict__ WlT, const float* __restrict__ bias,
    const u16* __restrict__ WrT, const void* xself, u16* out, int N) {
    __shared__ u16 sW[2 * 128 * 128];  // 64 KB
    u16* sW0 = sW;
    u16* sW1 = sW + 128 * 128;
    constexpr int SWA = 31;
    constexpr int SWS = (KS == 128) ? 31 : 15;
    f32x16 acc[2];
    const int lane = threadIdx.x & 63, wid = threadIdx.x >> 6;
    const int lm = lane & 31, hi = lane >> 5;
    const int rb = wid >> 1, cb0 = (wid & 1) * 2;
    const int rowBase = blockIdx.x * 128;
    const int arow = min(rowBase + rb * 32 + lm, N - 1);
#pragma unroll
    for (int t = 0; t < 2; ++t) {
        float bv = bias[(cb0 + t) * 32 + lm];
#pragma unroll
        for (int i = 0; i < 16; ++i) acc[t][i] = bv;
    }
    stage_w_swz<KA, SWA>(WlT, sW0);
    stage_w_swz<KS, SWS>(WrT, sW1);
    __syncthreads();
#pragma unroll
    for (int kc = 0; kc < KA; kc += 16) {
        const int e = kc + 4 * hi;
        s16x8 aA = afrag_bf(agg, KA, arow, e);
        s16x8 aS;
        if (kc < KS) {
            if constexpr (SELF_F32) aS = afrag_f32((const float*)xself, KS, arow, e);
            else aS = afrag_bf((const u16*)xself, KS, arow, e);
        }
#pragma unroll
        for (int t = 0; t < 2; ++t) {
            const int n = (cb0 + t) * 32 + lm;
            acc[t] = __builtin_amdgcn_mfma_f32_32x32x16_bf16(aA, bfrag<SWA>(sW0, n, e), acc[t], 0, 0, 0);
            if (kc < KS)
                acc[t] = __builtin_amdgcn_mfma_f32_32x32x16_bf16(aS, bfrag<SWS>(sW1, n, e), acc[t], 0, 0, 0);
        }
    }
    __syncthreads();  // in-place safety: all self reads complete before any writes
#pragma unroll
    for (int t = 0; t < 2; ++t) {
        int colv = (cb0 + t) * 32 + lm;
#pragma unroll
        for (int r = 0; r < 16; ++r) {
            int row = rowBase + rb * 32 + (r & 3) + 8 * (r >> 2) + 4 * hi;
            if (row < N) out[(size_t)row * 128 + colv] = f2bf(fmaxf(acc[t][r], 0.f));
        }
    }
}

// item: out = relu(0.5*(aggA@WlA + aggB@WlB + self@Wsum + bA + bB)); out != inputs
template<int KA, int KB, int KS>
__global__ __launch_bounds__(512, 4) void item_upd512(
    const u16* __restrict__ aggA, const u16* __restrict__ WlAT, const float* __restrict__ bA,
    const u16* __restrict__ aggB, const u16* __restrict__ WlBT, const float* __restrict__ bB,
    const u16* __restrict__ WsumT, const u16* __restrict__ xself,
    u16* __restrict__ out, int N) {
    __shared__ u16 sW[2 * 128 * 128];  // 64 KB
    u16* sW0 = sW;
    u16* sW1 = sW + 128 * 128;
    constexpr int SWA = (KA == 128) ? 31 : 15;
    constexpr int SWB = 31;
    constexpr int SWS = 31;
    f32x16 acc[2];
    const int lane = threadIdx.x & 63, wid = threadIdx.x >> 6;
    const int lm = lane & 31, hi = lane >> 5;
    const int rb = wid >> 1, cb0 = (wid & 1) * 2;
    const int rowBase = blockIdx.x * 128;
    const int arow = min(rowBase + rb * 32 + lm, N - 1);
#pragma unroll
    for (int t = 0; t < 2; ++t) {
        int cv = (cb0 + t) * 32 + lm;
        float bv = bA[cv] + bB[cv];
#pragma unroll
        for (int i = 0; i < 16; ++i) acc[t][i] = bv;
    }
    stage_w_swz<KA, SWA>(WlAT, sW0);
    stage_w_swz<KB, SWB>(WlBT, sW1);
    __syncthreads();
#pragma unroll
    for (int kc = 0; kc < KB; kc += 16) {
        const int e = kc + 4 * hi;
        s16x8 aB = afrag_bf(aggB, KB, arow, e);
        s16x8 aA;
        if (kc < KA) aA = afrag_bf(aggA, KA, arow, e);
#pragma unroll
        for (int t = 0; t < 2; ++t) {
            const int n = (cb0 + t) * 32 + lm;
            acc[t] = __builtin_amdgcn_mfma_f32_32x32x16_bf16(aB, bfrag<SWB>(sW1, n, e), acc[t], 0, 0, 0);
            if (kc < KA)
                acc[t] = __builtin_amdgcn_mfma_f32_32x32x16_bf16(aA, bfrag<SWA>(sW0, n, e), acc[t], 0, 0, 0);
        }
    }
    __syncthreads();  // all reads of sW0 done
    stage_w_swz<KS, SWS>(WsumT, sW0);
    __syncthreads();
#pragma unroll
    for (int kc = 0; kc < KS; kc += 16) {
        const int e = kc + 4 * hi;
        s16x8 aS = afrag_bf(xself, KS, arow, e);
#pragma unroll
        for (int t = 0; t < 2; ++t) {
            const int n = (cb0 + t) * 32 + lm;
            acc[t] = __builtin_amdgcn_mfma_f32_32x32x16_bf16(aS, bfrag<SWS>(sW0, n, e), acc[t], 0, 0, 0);
        }
    }
#pragma unroll
    for (int t = 0; t < 2; ++t) {
        int colv = (cb0 + t) * 32 + lm;
#pragma unroll
        for (int r = 0; r < 16; ++r) {
            int row = rowBase + rb * 32 + (r & 3) + 8 * (r >> 2) + 4 * hi;
            if (row < N) out[(size_t)row * 128 + colv] = f2bf(fmaxf(0.5f * acc[t][r], 0.f));
        }
    }
}

// ================= final 128->64 linear, f32 out (rounds 11-14, verified) =================
template<int K, int NCOL>
__device__ inline void stage_w_sap(const u16* __restrict__ Wt, u16* sW) {
    constexpr int CH = K / 4;
    constexpr int TOT = NCOL * CH;
#pragma unroll
    for (int i = threadIdx.x; i < TOT; i += 256) {
        int n = i / CH, c = i - n * CH;
        *reinterpret_cast<u16x4*>(sW + n * SAP + c * 4) =
            *reinterpret_cast<const u16x4*>(Wt + (size_t)n * K + c * 4);
    }
}

__global__ __launch_bounds__(256, 4) void final_upd(
    const u16* __restrict__ x, const u16* __restrict__ WfT, const float* __restrict__ bias,
    float* __restrict__ out, int N) {
    __shared__ u16 sW[64 * SAP];
    f32x16 acc;
    const int lane = threadIdx.x & 63, wid = threadIdx.x >> 6;
    const int lm = lane & 31, hi = lane >> 5;
    const int rb = wid / 2;
    const int rowBase = blockIdx.x * 64;
    const int arow = min(rowBase + rb * 32 + lm, N - 1);
    {
        float bv = bias[(wid % 2) * 32 + lm];
#pragma unroll
        for (int i = 0; i < 16; ++i) acc[i] = bv;
    }
    stage_w_sap<128, 64>(WfT, sW);
    __syncthreads();
    const int cb = wid % 2;
#pragma unroll
    for (int kc = 0; kc < 128; kc += 16) {
        const int e = kc + 4 * hi;
        s16x8 a = afrag_bf(x, 128, arow, e);
        const u16* pb = sW + (cb * 32 + lm) * SAP + e;
        s16x4 r0 = *reinterpret_cast<const s16x4*>(pb);
        s16x4 r1 = *reinterpret_cast<const s16x4*>(pb + 8);
        s16x8 b = { r0.x, r0.y, r0.z, r0.w, r1.x, r1.y, r1.z, r1.w };
        acc = __builtin_amdgcn_mfma_f32_32x32x16_bf16(a, b, acc, 0, 0, 0);
    }
    {
        int colv = cb * 32 + lm;
#pragma unroll
        for (int r = 0; r < 16; ++r) {
            int row = rowBase + rb * 32 + (r & 3) + 8 * (r >> 2) + 4 * hi;
            if (row < N) out[(size_t)row * 64 + colv] = acc[r];
        }
    }
}

// ================= host =================
extern "C" void kernel_launch(void* const* d_in, const int* in_sizes, int n_in,
                              void* d_out, int out_size, void* d_ws, size_t ws_size,
                              hipStream_t stream) {
    const float* x_user = (const float*)d_in[0];
    const float* x_item = (const float*)d_in[1];
    const int* ub_src = (const int*)d_in[2];
    const int* ub_dst = (const int*)d_in[3];
    const int* iu_src = (const int*)d_in[4];
    const int* iu_dst = (const int*)d_in[5];
    const int* ii_src = (const int*)d_in[6];
    const int* ii_dst = (const int*)d_in[7];
    const float* W1l_ub = (const float*)d_in[8];
    const float* W1r_ub = (const float*)d_in[9];
    const float* b1_ub = (const float*)d_in[10];
    const float* W1l_iu = (const float*)d_in[11];
    const float* W1r_iu = (const float*)d_in[12];
    const float* b1_iu = (const float*)d_in[13];
    const float* W1l_ii = (const float*)d_in[14];
    const float* W1r_ii = (const float*)d_in[15];
    const float* b1_ii = (const float*)d_in[16];
    const float* W23l = (const float*)d_in[17];
    const float* W23r = (const float*)d_in[18];
    const float* b23 = (const float*)d_in[19];
    const float* Wf_user = (const float*)d_in[20];
    const float* bf_user = (const float*)d_in[21];
    const float* Wf_item = (const float*)d_in[22];
    const float* bf_item = (const float*)d_in[23];

    // ---- workspace (round-14 layout + merged-prep arrays) ----
    char* p = (char*)d_ws;
    u16* xu_bf  = (u16*)p;  p += (size_t)NU_ * 128 * 2;   // 51.2 MB
    u16* xiA_bf = (u16*)p;  p += (size_t)NI_ * 128 * 2;   // 25.6
    u16* xi0_bf = (u16*)p;  p += (size_t)NI_ * 128 * 2;   // 25.6 (x_item bf16)
    u16* agg_ub = (u16*)p;  p += (size_t)NI_ * 128 * 2;   // 25.6 (deg3 alias pre-gather)
    u16* agg_ii = (u16*)p;  p += (size_t)NI_ * 128 * 2;   // 25.6
    u16* wt     = (u16*)p;  p += (size_t)344064 * 2;      // 0.69
    float* inv3 = (float*)p; p += (size_t)(NU_ + 2 * NI_) * 4;
    int* rp_iu = (int*)p;  p += (size_t)(NU_ + 4) * 4;
    int* rp_ub = (int*)p;  p += (size_t)(NI_ + 4) * 4;
    int* rp_ii = (int*)p;  p += (size_t)(NI_ + 4) * 4;
    int* col_iu = (int*)p; p += (size_t)E_IU * 4;
    int* col_ub = (int*)p; p += (size_t)E_UB * 4;
    int* col_ii = (int*)p; p += (size_t)E_II * 4;
    int* bsum3 = (int*)p;  p += 3 * 256 * 4;
    u16* xu0b = nullptr;  // optional bf16 x_user
    {
        size_t used = (size_t)(p - (char*)d_ws);
        if (used + (size_t)NU_ * 64 * 2 <= ws_size) xu0b = (u16*)p;
    }
    float* inv_iu = inv3;
    float* inv_ub = inv3 + NU_;
    float* inv_ii = inv3 + NU_ + NI_;
    // deg3 aliases agg_ub region (CSR build completes before gathers write aggs)
    int* deg3 = (int*)agg_ub;
    int* deg_iu = deg3, *deg_ub = deg3 + NU_, *deg_ii = deg3 + NU_ + NI_;
    // d_out: agg_iu [NU][128] bf16 + xiB [NI][128] bf16; dead before finals write
    u16* agg_iu = (u16*)d_out;
    u16* xiB_bf = (u16*)((char*)d_out + (size_t)NU_ * 128 * 2);

    // weight slots (bf16, transposed [N][K])
    u16* wt_W1l_ub = wt + 0;
    u16* wt_W1l_iu = wt + 24576;
    u16* wt_W1r_iu = wt + 40960;
    u16* wt_W1l_ii = wt + 49152;
    u16* wt_W23l   = wt + 81920;    // 6 x 16384
    u16* wt_W23r   = wt + 180224;   // 6 x 16384
    u16* wt_Wf_u   = wt + 278528;
    u16* wt_Wf_i   = wt + 286720;
    u16* wt_Wsum   = wt + 294912;   // 3 x 16384

    // ---- CSR build (merged) ----
    hipMemsetAsync(deg3, 0, (size_t)(NU_ + 2 * NI_) * 4, stream);
    const int Etot = E_IU + E_UB + E_II;
    deg_all<<<(Etot + 255) / 256, 256, 0, stream>>>(iu_dst, E_IU, deg_iu, ub_dst, E_UB, deg_ub,
                                                    ii_dst, E_II, deg_ii);
    const int NB = 196;  // ceil(NU/1024)
    scanA_all<<<dim3(NB, 3), 256, 0, stream>>>(deg_iu, NU_, deg_ub, NI_, deg_ii, NI_, bsum3);
    scanB_all<<<3, 256, 0, stream>>>(bsum3, NB);
    scanC_all<<<dim3(NB, 3), 256, 0, stream>>>(deg_iu, NU_, rp_iu, E_IU,
                                               deg_ub, NI_, rp_ub, E_UB,
                                               deg_ii, NI_, rp_ii, E_II, bsum3);
    inv_all<<<(NU_ + 2 * NI_ + 255) / 256, 256, 0, stream>>>(deg3, inv3, NU_ + 2 * NI_);
    hipMemsetAsync(deg3, 0, (size_t)(NU_ + 2 * NI_) * 4, stream);  // cursors
    fill_all<<<(Etot + 255) / 256, 256, 0, stream>>>(
        iu_src, iu_dst, E_IU, rp_iu, deg_iu, col_iu,
        ub_src, ub_dst, E_UB, rp_ub, deg_ub, col_ub,
        ii_src, ii_dst, E_II, rp_ii, deg_ii, col_ii);

    // ---- conversions (merged weight prep) ----
    cvt_kernel<<<(NI_ * 32 + 255) / 256, 256, 0, stream>>>(x_item, xi0_bf, NI_ * 32);
    if (xu0b) cvt_kernel<<<(NU_ * 16 + 255) / 256, 256, 0, stream>>>(x_user, xu0b, NU_ * 16);
    {
        WtJobs J;
        int idx = 0;
        J.j[idx++] = { W1l_ub, nullptr, wt_W1l_ub, 64, 128 };
        J.j[idx++] = { W1l_iu, nullptr, wt_W1l_iu, 128, 128 };
        J.j[idx++] = { W1r_iu, nullptr, wt_W1r_iu, 64, 128 };
        J.j[idx++] = { W1l_ii, nullptr, wt_W1l_ii, 128, 128 };
        for (int m = 0; m < 6; ++m) J.j[idx++] = { W23l + (size_t)m * 16384, nullptr, wt_W23l + (size_t)m * 16384, 128, 128 };
        for (int m = 0; m < 6; ++m) J.j[idx++] = { W23r + (size_t)m * 16384, nullptr, wt_W23r + (size_t)m * 16384, 128, 128 };
        J.j[idx++] = { Wf_user, nullptr, wt_Wf_u, 128, 64 };
        J.j[idx++] = { Wf_item, nullptr, wt_Wf_i, 128, 64 };
        J.j[idx++] = { W1r_ub, W1r_ii, wt_Wsum + 0, 128, 128 };
        J.j[idx++] = { W23r + 0 * 16384, W23r + 2 * 16384, wt_Wsum + 16384, 128, 128 };
        J.j[idx++] = { W23r + 3 * 16384, W23r + 5 * 16384, wt_Wsum + 32768, 128, 128 };
        wt_all<<<dim3(64, 21), 256, 0, stream>>>(J);
    }

    const int gU2 = (NU_ + 127) / 128;  // 1563
    const int gI2 = (NI_ + 127) / 128;  // 782
    const int gUf = (NU_ + 63) / 64, gIf = (NI_ + 63) / 64;
    const int ggI_b128 = (NI_ * 16 + 255) / 256;
    const int ggU_b128 = (NU_ * 16 + 255) / 256;
    const int ggI_b64  = (NI_ * 8 + 255) / 256;
    const int ggI_f64  = (NI_ * 16 + 255) / 256;

    // ---- layer 1 ----
    if (xu0b)
        gather_kernel<64, false><<<ggI_b64, 256, 0, stream>>>(xu0b, rp_ub, col_ub, inv_ub, agg_ub, NI_);
    else
        gather_kernel<64, true><<<ggI_f64, 256, 0, stream>>>(x_user, rp_ub, col_ub, inv_ub, agg_ub, NI_);
    gather_kernel<128, false><<<ggI_b128, 256, 0, stream>>>(xi0_bf, rp_ii, col_ii, inv_ii, agg_ii, NI_);
    gather_kernel<128, false><<<ggU_b128, 256, 0, stream>>>(xi0_bf, rp_iu, col_iu, inv_iu, agg_iu, NU_);
    item_upd512<64, 128, 128><<<gI2, 512, 0, stream>>>(
        agg_ub, wt_W1l_ub, b1_ub, agg_ii, wt_W1l_ii, b1_ii,
        wt_Wsum + 0, xi0_bf, xiA_bf, NI_);
    if (xu0b)
        user_upd512<128, 64, false><<<gU2, 512, 0, stream>>>(
            agg_iu, wt_W1l_iu, b1_iu, wt_W1r_iu, xu0b, xu_bf, NU_);
    else
        user_upd512<128, 64, true><<<gU2, 512, 0, stream>>>(
            agg_iu, wt_W1l_iu, b1_iu, wt_W1r_iu, x_user, xu_bf, NU_);

    // ---- layers 2-3 ----
    for (int l = 0; l < 2; ++l) {
        const u16* cur = (l == 0) ? xiA_bf : xiB_bf;
        u16* nxt = (l == 0) ? xiB_bf : xiA_bf;
        const u16* wl_ub = wt_W23l + (size_t)(l * 3 + 0) * 16384;
        const u16* wl_iu = wt_W23l + (size_t)(l * 3 + 1) * 16384;
        const u16* wr_iu = wt_W23r + (size_t)(l * 3 + 1) * 16384;
        const u16* wl_ii = wt_W23l + (size_t)(l * 3 + 2) * 16384;
        const u16* wsum = wt_Wsum + (size_t)(l + 1) * 16384;
        const float* b_ub = b23 + (size_t)(l * 3 + 0) * 128;
        const float* b_iu = b23 + (size_t)(l * 3 + 1) * 128;
        const float* b_ii = b23 + (size_t)(l * 3 + 2) * 128;

        gather_kernel<128, false><<<ggI_b128, 256, 0, stream>>>(xu_bf, rp_ub, col_ub, inv_ub, agg_ub, NI_);
        gather_kernel<128, false><<<ggI_b128, 256, 0, stream>>>(cur, rp_ii, col_ii, inv_ii, agg_ii, NI_);
        gather_kernel<128, false><<<ggU_b128, 256, 0, stream>>>(cur, rp_iu, col_iu, inv_iu, agg_iu, NU_);
        item_upd512<128, 128, 128><<<gI2, 512, 0, stream>>>(
            agg_ub, wl_ub, b_ub, agg_ii, wl_ii, b_ii,
            wsum, cur, nxt, NI_);
        user_upd512<128, 128, false><<<gU2, 512, 0, stream>>>(
            agg_iu, wl_iu, b_iu, wr_iu, xu_bf, xu_bf, NU_);
    }

    // ---- finals (layer-3 item output = xiA_bf); overwrite agg_iu/xiB (dead) ----
    float* out = (float*)d_out;
    final_upd<<<gUf, 256, 0, stream>>>(xu_bf, wt_Wf_u, bf_user, out, NU_);
    final_upd<<<gIf, 256, 0, stream>>>(xiA_bf, wt_Wf_i, bf_item, out + (size_t)NU_ * 64, NI_);
}